// Round 14
// baseline (170.496 us; speedup 1.0000x reference)
//
#include <hip/hip_runtime.h>

// GCN layer: out = relu(x @ W_self^T + b_self + segment_mean(x[src], dst) @ W_neigh^T)
// N = 100000 nodes, D = 64, E = 1.25M edges.
//
// R3 structure: mean-then-matmul == matmul-then-mean (linearity).
// y = x@Ws^T + b and z = x@Wn^T computed FIRST (bf16 planes); gather averages
// z rows and finishes out = relu(y + mean).
// R4 lesson: per-edge scattered 4B global writes = 16x write amplification.
// R6 lesson: __shfl with divergent-exit loops is UB on gfx950 — all shfl loops
//   use wave-uniform trip counts with predication.
// R7-R13 lessons: seven theories for the front kernel's ~44 µs falsified
//   (LDS contention, block shape, claim storm, dispatch count, fusion, TLP,
//   store queue). The GEMM role was NEVER isolated — every variant contained
//   it. R11: fat-block fusion caps TLP for the gather (keep many small blocks).
//
// R14: role reshuffle at the SAME dispatch count — isolates the GEMM.
//   D1 k_scatter : scatter ALONE (306 blocks x 256 thr): LDS-staged radix
//                  scatter into 196 buckets (contiguous-run claim, full-line
//                  ebuf writes). First clean measurement of scatter cost.
//   D2 k_gemm_csr: csr blocks FIRST (196 x 512 thr: window->regs, in-LDS
//                  node-sort, coalesced flush; LDS *int* atomics only — fp32
//                  LDS atomicAdd is a CAS-loop disaster), then 782 GEMM
//                  blocks (128 nodes each) fill the machine: dual MFMA ->
//                  bf16 y,z with LDS-transposed 16B stores. csr is
//                  independent of GEMM output -> its latency hides inside
//                  the GEMM's duration. LDS union 32 KB.
//   D3 gather_oct: 3125 blocks x 256 thr, oct-per-node, 8-deep z ILP +
//                  col-line prefetch (unchanged from R13).

#define BKSH 9                // log2(nodes per bucket)
#define BKN 512               // nodes per bucket
#define NBMAX 256             // >= NB = 196
#define CAPE 7168             // edge capacity per bucket (mean 6400, +9.6 sigma)
#define WPT (CAPE / BKN)      // window entries per thread in csr role = 14
#define CHUNK 4096            // edges per scatter block
#define EPT (CHUNK / 256)     // edges per thread in scatter = 16

typedef __attribute__((ext_vector_type(8))) short short8;
typedef __attribute__((ext_vector_type(4))) float floatx4;

// fp32 -> bf16 round-to-nearest-even, branch-free.
static __device__ inline unsigned short f2bf(float f) {
  union { float f; unsigned int u; } v;
  v.f = f;
  unsigned int r = v.u + 0x7FFFu + ((v.u >> 16) & 1u);
  return (unsigned short)(r >> 16);
}

static __device__ inline short8 pack8(float4 a, float4 b) {
  short8 s;
  s[0] = (short)f2bf(a.x); s[1] = (short)f2bf(a.y);
  s[2] = (short)f2bf(a.z); s[3] = (short)f2bf(a.w);
  s[4] = (short)f2bf(b.x); s[5] = (short)f2bf(b.y);
  s[6] = (short)f2bf(b.z); s[7] = (short)f2bf(b.w);
  return s;
}

// unpack 8 bf16 (4 dwords) and accumulate into 8 fp32.
static __device__ inline void add8(float* a, short8 sv) {
  union { short8 s; unsigned int u[4]; } c; c.s = sv;
#pragma unroll
  for (int i = 0; i < 4; ++i) {
    a[2 * i]     += __uint_as_float(c.u[i] << 16);
    a[2 * i + 1] += __uint_as_float(c.u[i] & 0xFFFF0000u);
  }
}

// unpack 8 bf16 into 8 fp32 (no accumulate).
static __device__ inline void cvt8(float* a, short8 sv) {
  union { short8 s; unsigned int u[4]; } c; c.s = sv;
#pragma unroll
  for (int i = 0; i < 4; ++i) {
    a[2 * i]     = __uint_as_float(c.u[i] << 16);
    a[2 * i + 1] = __uint_as_float(c.u[i] & 0xFFFF0000u);
  }
}

// D1: LDS-staged radix scatter, standalone (306 blocks).
__global__ __launch_bounds__(256) void k_scatter(
    const int* __restrict__ src, const int* __restrict__ dst,
    int* __restrict__ cursor, int* __restrict__ ebuf,
    int E, int NB) {
  __shared__ int h[NBMAX], loff[NBMAX], gbase[NBMAX];
  __shared__ int sbuf[CHUNK];
  int t = threadIdx.x;
  int bid = blockIdx.x;
  int w = t >> 6, lane = t & 63;

  if (t < NBMAX) h[t] = 0;
  __syncthreads();

  int base = bid * CHUNK;
  int myd[EPT], mys[EPT];
#pragma unroll
  for (int i = 0; i < EPT; ++i) {
    int e = base + t + 256 * i;  // coalesced
    if (e < E) {
      myd[i] = dst[e];
      mys[i] = src[e];
      atomicAdd(&h[myd[i] >> BKSH], 1);
    } else myd[i] = -1;
  }
  __syncthreads();

  if (t < 64) {  // wave 0: exclusive scan of h[0..255], 4 per lane
    int i0 = 4 * t;
    int v0 = h[i0], v1 = h[i0 + 1], v2 = h[i0 + 2], v3 = h[i0 + 3];
    int s4 = v0 + v1 + v2 + v3, inc = s4;
#pragma unroll
    for (int off = 1; off < 64; off <<= 1) {
      int u = __shfl_up(inc, off, 64);
      if (t >= off) inc += u;
    }
    int ex = inc - s4;
    loff[i0] = ex; loff[i0 + 1] = ex + v0;
    loff[i0 + 2] = ex + v0 + v1; loff[i0 + 3] = ex + v0 + v1 + v2;
  }
  __syncthreads();

  if (t < NB) {
    if (h[t] > 0) gbase[t] = t * CAPE + atomicAdd(&cursor[t], h[t]);  // claim
  }
  __syncthreads();
  if (t < NBMAX) h[t] = 0;  // reuse as local cursor
  __syncthreads();

#pragma unroll
  for (int i = 0; i < EPT; ++i) {
    if (myd[i] >= 0) {
      int b = myd[i] >> BKSH;
      int p = atomicAdd(&h[b], 1);           // LDS int atomic: native, fast
      sbuf[loff[b] + p] = mys[i] | ((myd[i] & (BKN - 1)) << 17);  // src < 2^17
    }
  }
  __syncthreads();

  for (int b = w; b < NB; b += 4) {
    int c = h[b], lo = loff[b], go = gbase[b];
    for (int j = lane; j < c; j += 64)
      ebuf[go + j] = sbuf[lo + j];
  }
}

// D2: csr role (blocks < NB) | GEMM role (128 nodes/block, 8 waves).
// csr is independent of GEMM output; its low-TLP latency hides inside the
// GEMM blocks' execution. Shared 32 KB LDS (union of the two roles).
__global__ __launch_bounds__(512) void k_gemm_csr(
    const float* __restrict__ x,
    const float* __restrict__ Wself, const float* __restrict__ bself,
    const float* __restrict__ Wneigh,
    unsigned short* __restrict__ yb, unsigned short* __restrict__ zb,
    const int* __restrict__ cursor, const int* __restrict__ ebuf,
    int* __restrict__ col, int2* __restrict__ rowse,
    int N, int NB) {
  __shared__ int shm[8192];  // 32 KB union
  int t = threadIdx.x;
  int bid = blockIdx.x;
  int lane = t & 63, w = t >> 6;

  if (bid >= NB) {
    // ---- GEMM role: y = x@Ws^T + b (bf16), z = x@Wn^T (bf16) ----
    // Per-wave-private [16][64] bf16 transpose tiles -> 16B short8 stores.
    int tb = (bid - NB) * 128 + w * 16;  // 8 waves x 16 nodes
    int m = lane & 15, q = lane >> 4;
    unsigned short* lds  = (unsigned short*)shm;
    unsigned short* ylds = lds + w * 2048;  // 4 KB per wave
    unsigned short* zlds = ylds + 1024;

    long long rowA = (long long)min(tb + m, N - 1) * 64;
    short8 ax[2];
#pragma unroll
    for (int ks = 0; ks < 2; ++ks) {
      const float* xr = &x[rowA + ks * 32 + q * 8];
      ax[ks] = pack8(*(const float4*)xr, *(const float4*)(xr + 4));
    }

#pragma unroll
    for (int nt = 0; nt < 4; ++nt) {
      int ob = nt * 16;
      long long rowB = (long long)(ob + m) * 64;
      floatx4 accs = {0.f, 0.f, 0.f, 0.f};
      floatx4 accn = {0.f, 0.f, 0.f, 0.f};
#pragma unroll
      for (int ks = 0; ks < 2; ++ks) {
        const float* pw = &Wself[rowB + ks * 32 + q * 8];
        short8 bs = pack8(*(const float4*)pw, *(const float4*)(pw + 4));
        accs = __builtin_amdgcn_mfma_f32_16x16x32_bf16(ax[ks], bs, accs, 0, 0, 0);
        const float* pn = &Wneigh[rowB + ks * 32 + q * 8];
        short8 bn = pack8(*(const float4*)pn, *(const float4*)(pn + 4));
        accn = __builtin_amdgcn_mfma_f32_16x16x32_bf16(ax[ks], bn, accn, 0, 0, 0);
      }
      float bias = bself[ob + m];
#pragma unroll
      for (int r = 0; r < 4; ++r) {
        int nl = q * 4 + r;
        ylds[nl * 64 + ob + m] = f2bf(accs[r] + bias);  // 2B LDS write (cheap)
        zlds[nl * 64 + ob + m] = f2bf(accn[r]);
      }
    }
    // wave-private slice: no barrier; compiler orders ds ops via lgkmcnt
    if (tb + (lane >> 2) < N) {  // lane covers 32B of node tb + lane/4
      long long go = (long long)tb * 64 + lane * 16;
      *(short8*)&yb[go]     = *(short8*)&ylds[lane * 16];
      *(short8*)&yb[go + 8] = *(short8*)&ylds[lane * 16 + 8];
      *(short8*)&zb[go]     = *(short8*)&zlds[lane * 16];
      *(short8*)&zb[go + 8] = *(short8*)&zlds[lane * 16 + 8];
    }
    return;
  }

  // ---- csr role: one 512-thread block per 512-node bucket ----
  int* sbuf = shm;              // CAPE ints = 28672 B
  int* cnt  = shm + CAPE;       // BKN ints
  int* wsum = shm + CAPE + BKN; // 8 ints  (total 30.8 KB < 32 KB)
  int b = bid;
  int s = b * CAPE;
  int n = cursor[b];
  int e = s + n;

  // stage window into registers (static indices -> stays in VGPRs)
  int my[WPT];
#pragma unroll
  for (int i = 0; i < WPT; ++i) {
    int j = s + t + i * BKN;
    my[i] = (j < e) ? ebuf[j] : -1;  // entries < 2^26, -1 is a safe sentinel
  }

  cnt[t] = 0;
  __syncthreads();
#pragma unroll
  for (int i = 0; i < WPT; ++i)
    if (my[i] >= 0) atomicAdd(&cnt[(my[i] >> 17) & (BKN - 1)], 1);
  __syncthreads();

  // block exclusive scan over 512 (1 per thread, 8 waves)
  int v = cnt[t];
  int inc = v;
#pragma unroll
  for (int o = 1; o < 64; o <<= 1) {
    int u = __shfl_up(inc, o, 64);
    if (lane >= o) inc += u;
  }
  if (lane == 63) wsum[w] = inc;
  __syncthreads();
  if (t < 8) {
    int s0 = wsum[t], incw = s0;
#pragma unroll
    for (int o = 1; o < 8; o <<= 1) {
      int u = __shfl_up(incw, o, 64);
      if (t >= o) incw += u;
    }
    wsum[t] = incw - s0;
  }
  __syncthreads();
  int ex = wsum[w] + inc - v;
  int node = (b << BKSH) + t;
  if (node < N) rowse[node] = make_int2(s + ex, v);
  __syncthreads();
  cnt[t] = ex;  // seed scatter cursor with exclusive prefix
  __syncthreads();

  // in-LDS node-sort: atomic result is the final position in the window
#pragma unroll
  for (int i = 0; i < WPT; ++i) {
    if (my[i] >= 0) {
      int nl = (my[i] >> 17) & (BKN - 1);
      int p = atomicAdd(&cnt[nl], 1);
      sbuf[p] = my[i] & 0x1FFFF;
    }
  }
  __syncthreads();

  // coalesced flush
  for (int j = t; j < n; j += BKN) col[s + j] = sbuf[j];
}

// D3: oct-per-node gather (unchanged from R13). 32 nodes/block (4 waves x 8
// octs). Lane owns 8 dims of its node -> no cross-lane reduce. Per 8 edges:
// one 32B col-line fetch per oct (prefetched one iteration ahead), then 8
// independent z-row loads. Loop bound = wave-max degree (uniform, shfl-safe);
// predicated-off lanes load z row 0 (L1-hot). All-64-lane epilogue writes.
__global__ __launch_bounds__(256) void gather_oct(
    const unsigned short* __restrict__ zb,
    const int2* __restrict__ rowse,
    const int* __restrict__ col,
    const unsigned short* __restrict__ yb,
    float* __restrict__ out, int N) {
  int t = threadIdx.x;
  int lane = t & 63, w = t >> 6;
  int o = lane >> 3, d = lane & 7;
  int node = blockIdx.x * 32 + w * 8 + o;

  int2 se = rowse[min(node, N - 1)];  // 8 lanes/oct same addr -> broadcast
  int s0 = se.x;
  int c = (node < N) ? se.y : 0;
  int cm1 = max(c - 1, 0);

  // wave-max degree (uniform trip count for the shfl loop)
  int cmax = c;
#pragma unroll
  for (int m = 8; m <= 32; m <<= 1) cmax = max(cmax, __shfl_xor(cmax, m, 64));

  long long ro = (long long)node * 64 + d * 8;
  long long ros = (long long)min(node, N - 1) * 64 + d * 8;
  short8 yv8 = *(const short8*)&yb[ros];  // prefetch, independent of edge loop

  float a[8] = {0.f, 0.f, 0.f, 0.f, 0.f, 0.f, 0.f, 0.f};
  float b2[8] = {0.f, 0.f, 0.f, 0.f, 0.f, 0.f, 0.f, 0.f};
  int colv = col[s0 + min(d, cm1)];  // first 32B line per oct
  for (int kb = 0; kb < cmax; kb += 8) {  // cmax wave-uniform
    int colv_nx = 0;
    if (kb + 8 < cmax) colv_nx = col[s0 + min(kb + 8 + d, cm1)];  // prefetch
#pragma unroll
    for (int j = 0; j < 8; ++j) {
      bool p = (kb + j) < c;  // oct-uniform predicate
      int cs = __shfl(colv, (lane & 56) | j, 64);  // all lanes active
      cs = p ? cs : 0;
      short8 v = *(const short8*)&zb[(long long)cs * 64 + d * 8];
      if (p) add8((j & 1) ? b2 : a, v);
    }
    colv = colv_nx;
  }
#pragma unroll
  for (int k = 0; k < 8; ++k) a[k] += b2[k];

  if (node < N) {
    float inv = 1.0f / fmaxf((float)c, 1.0f);
    float yv[8];
    cvt8(yv, yv8);
    float4 r0, r1;
    r0.x = fmaxf(yv[0] + a[0] * inv, 0.f);
    r0.y = fmaxf(yv[1] + a[1] * inv, 0.f);
    r0.z = fmaxf(yv[2] + a[2] * inv, 0.f);
    r0.w = fmaxf(yv[3] + a[3] * inv, 0.f);
    r1.x = fmaxf(yv[4] + a[4] * inv, 0.f);
    r1.y = fmaxf(yv[5] + a[5] * inv, 0.f);
    r1.z = fmaxf(yv[6] + a[6] * inv, 0.f);
    r1.w = fmaxf(yv[7] + a[7] * inv, 0.f);
    *(float4*)&out[ro] = r0;
    *(float4*)&out[ro + 4] = r1;
  }
}

extern "C" void kernel_launch(void* const* d_in, const int* in_sizes, int n_in,
                              void* d_out, int out_size, void* d_ws, size_t ws_size,
                              hipStream_t stream) {
  const float* x      = (const float*)d_in[0];
  const int*   eidx   = (const int*)d_in[1];
  const float* Wself  = (const float*)d_in[2];
  const float* bself  = (const float*)d_in[3];
  const float* Wneigh = (const float*)d_in[4];
  float* out = (float*)d_out;

  const int N = in_sizes[0] / 64;
  const int E = in_sizes[1] / 2;
  const int* src = eidx;      // edge_index row 0
  const int* dst = eidx + E;  // edge_index row 1
  const int NB = (N + BKN - 1) / BKN;       // 196 buckets of 512 nodes
  const int SCB = (E + CHUNK - 1) / CHUNK;  // 306 scatter blocks

  // ws layout: yb bf16[N*64] | zb bf16[N*64] | cursor[256] | rowse int2[N]
  //            | ebuf[NB*CAPE] | col[NB*CAPE]   (~38 MB)
  unsigned short* yb = (unsigned short*)d_ws;
  unsigned short* zb = yb + (size_t)N * 64;
  int* cursor = (int*)(zb + (size_t)N * 64);
  int2* rowse = (int2*)(cursor + NBMAX);
  int* ebuf   = (int*)(rowse + N);
  int* col    = ebuf + (size_t)NB * CAPE;

  hipMemsetAsync(cursor, 0, NBMAX * sizeof(int), stream);

  const int GB = (N + 127) / 128;  // 782 GEMM blocks (128 nodes each)
  k_scatter<<<SCB, 256, 0, stream>>>(src, dst, cursor, ebuf, E, NB);
  k_gemm_csr<<<NB + GB, 512, 0, stream>>>(x, Wself, bself, Wneigh, yb, zb,
                                          cursor, ebuf, col, rowse, N, NB);
  gather_oct<<<(N + 31) / 32, 256, 0, stream>>>(zb, rowse, col, yb, out, N);
}

// Round 15
// 157.603 us; speedup vs baseline: 1.0818x; 1.0818x over previous
//
#include <hip/hip_runtime.h>

// GCN layer: out = relu(x @ W_self^T + b_self + segment_mean(x[src], dst) @ W_neigh^T)
// N = 100000 nodes, D = 64, E = 1.25M edges.
//
// R3 structure: mean-then-matmul == matmul-then-mean (linearity).
// y = x@Ws^T + b and z = x@Wn^T computed FIRST (bf16 planes); gather averages
// z rows and finishes out = relu(y + mean).
// R4 lesson: per-edge scattered 4B global writes = 16x write amplification.
// R6 lesson: __shfl with divergent-exit loops is UB on gfx950 — all shfl loops
//   use wave-uniform trip counts with predication.
// R7-R14 lessons: eight theories for the front kernel falsified; R14 isolation
//   showed scatter~33 + GEMM~40 SERIALIZED loses ~14 µs vs R13's fused k1 (44)
//   -> keep the scatter||GEMM fusion. R11: fat low-count blocks starve TLP.
//
// R15: R13 base + HALF-BUCKET csr (R11's mechanism applied in reverse):
//   sb_csr was 196 x 512-thr blocks = 1 block/CU on 196 CUs, 60 idle, no
//   co-resident block to hide its serial LDS-atomic chains. csr_half: 392
//   blocks; block bh sorts half (bh&1) of bucket (bh>>1): reads the full
//   window, filters to its 256 nodes, sorts into a PRIVATE col sub-window
//   (bh*CAPH) -> no cross-half coupling; rowse carries absolute offsets so
//   the gather is unchanged.
//
// Pipeline (memset + 3 kernels):
//   memset      : cursor[256] = 0.
//   k1_main     : blocks [0,SCB): LDS-staged radix scatter into 196 buckets
//                 (contiguous-run claim, full-line ebuf writes). Blocks
//                 [SCB,+GB): dual MFMA GEMM -> bf16 y,z, LDS-transposed 16B
//                 stores. (43.7 µs measured; resisted 8 theories — frozen.)
//   csr_half    : 392 blocks x 512 thr as above. LDS *int* atomics only
//                 (fp32 LDS atomicAdd = CAS-loop disaster).
//   gather_oct  : 3125 blocks x 256 thr, oct-per-node, 8-deep z ILP +
//                 col-line prefetch (unchanged from R13).

#define BKSH 9                // log2(nodes per bucket)
#define BKN 512               // nodes per bucket
#define NBMAX 256             // >= NB = 196
#define CAPE 7168             // edge capacity per bucket (mean 6400, +9.6 sigma)
#define CAPH 4608             // col capacity per HALF bucket (mean 3200, +25 sigma)
#define WPT (CAPE / BKN)      // window entries per thread in csr role = 14
#define CHUNK 4096            // edges per scatter block
#define EPT (CHUNK / 256)     // edges per thread in scatter = 16

typedef __attribute__((ext_vector_type(8))) short short8;
typedef __attribute__((ext_vector_type(4))) float floatx4;

// fp32 -> bf16 round-to-nearest-even, branch-free.
static __device__ inline unsigned short f2bf(float f) {
  union { float f; unsigned int u; } v;
  v.f = f;
  unsigned int r = v.u + 0x7FFFu + ((v.u >> 16) & 1u);
  return (unsigned short)(r >> 16);
}

static __device__ inline short8 pack8(float4 a, float4 b) {
  short8 s;
  s[0] = (short)f2bf(a.x); s[1] = (short)f2bf(a.y);
  s[2] = (short)f2bf(a.z); s[3] = (short)f2bf(a.w);
  s[4] = (short)f2bf(b.x); s[5] = (short)f2bf(b.y);
  s[6] = (short)f2bf(b.z); s[7] = (short)f2bf(b.w);
  return s;
}

// unpack 8 bf16 (4 dwords) and accumulate into 8 fp32.
static __device__ inline void add8(float* a, short8 sv) {
  union { short8 s; unsigned int u[4]; } c; c.s = sv;
#pragma unroll
  for (int i = 0; i < 4; ++i) {
    a[2 * i]     += __uint_as_float(c.u[i] << 16);
    a[2 * i + 1] += __uint_as_float(c.u[i] & 0xFFFF0000u);
  }
}

// unpack 8 bf16 into 8 fp32 (no accumulate).
static __device__ inline void cvt8(float* a, short8 sv) {
  union { short8 s; unsigned int u[4]; } c; c.s = sv;
#pragma unroll
  for (int i = 0; i < 4; ++i) {
    a[2 * i]     = __uint_as_float(c.u[i] << 16);
    a[2 * i + 1] = __uint_as_float(c.u[i] & 0xFFFF0000u);
  }
}

// Fused: edge radix-scatter (blocks < SCB) | dual-GEMM y,z from fp32 x.
__global__ __launch_bounds__(256) void k1_main(
    const float* __restrict__ x,
    const float* __restrict__ Wself, const float* __restrict__ bself,
    const float* __restrict__ Wneigh,
    unsigned short* __restrict__ yb, unsigned short* __restrict__ zb,
    const int* __restrict__ src, const int* __restrict__ dst,
    int* __restrict__ cursor, int* __restrict__ ebuf,
    int E, int N, int NB, int SCB) {
  __shared__ int h[NBMAX], loff[NBMAX], gbase[NBMAX];
  __shared__ int sbuf[CHUNK];
  int t = threadIdx.x;
  int bid = blockIdx.x;

  if (bid >= SCB) {
    // ---- GEMM role: y = x@Ws^T + b (bf16), z = x@Wn^T (bf16) ----
    // Per-wave-private [16][64] bf16 transpose tiles in sbuf -> 16B stores.
    int lane = t & 63;
    int w = t >> 6;
    int tb = (bid - SCB) * 64 + w * 16;
    int m = lane & 15, q = lane >> 4;
    unsigned short* lds  = (unsigned short*)sbuf;  // 8192 ushorts
    unsigned short* ylds = lds + w * 2048;         // [16 nodes][64 cols]
    unsigned short* zlds = ylds + 1024;

    long long rowA = (long long)min(tb + m, N - 1) * 64;
    short8 ax[2];
#pragma unroll
    for (int ks = 0; ks < 2; ++ks) {
      const float* xr = &x[rowA + ks * 32 + q * 8];
      ax[ks] = pack8(*(const float4*)xr, *(const float4*)(xr + 4));
    }

#pragma unroll
    for (int nt = 0; nt < 4; ++nt) {
      int ob = nt * 16;
      long long rowB = (long long)(ob + m) * 64;
      floatx4 accs = {0.f, 0.f, 0.f, 0.f};
      floatx4 accn = {0.f, 0.f, 0.f, 0.f};
#pragma unroll
      for (int ks = 0; ks < 2; ++ks) {
        const float* pw = &Wself[rowB + ks * 32 + q * 8];
        short8 bs = pack8(*(const float4*)pw, *(const float4*)(pw + 4));
        accs = __builtin_amdgcn_mfma_f32_16x16x32_bf16(ax[ks], bs, accs, 0, 0, 0);
        const float* pn = &Wneigh[rowB + ks * 32 + q * 8];
        short8 bn = pack8(*(const float4*)pn, *(const float4*)(pn + 4));
        accn = __builtin_amdgcn_mfma_f32_16x16x32_bf16(ax[ks], bn, accn, 0, 0, 0);
      }
      float bias = bself[ob + m];
#pragma unroll
      for (int r = 0; r < 4; ++r) {
        int nl = q * 4 + r;
        ylds[nl * 64 + ob + m] = f2bf(accs[r] + bias);  // 2B LDS write (cheap)
        zlds[nl * 64 + ob + m] = f2bf(accn[r]);
      }
    }
    // wave-private slice: no barrier; compiler orders ds ops via lgkmcnt
    if (tb + (lane >> 2) < N) {  // lane covers 32B of node tb + lane/4
      long long go = (long long)tb * 64 + lane * 16;
      *(short8*)&yb[go]     = *(short8*)&ylds[lane * 16];
      *(short8*)&yb[go + 8] = *(short8*)&ylds[lane * 16 + 8];
      *(short8*)&zb[go]     = *(short8*)&zlds[lane * 16];
      *(short8*)&zb[go + 8] = *(short8*)&zlds[lane * 16 + 8];
    }
    return;
  }

  // ---- scatter role ----
  int w = t >> 6, lane = t & 63;
  if (t < NBMAX) h[t] = 0;
  __syncthreads();

  int base = bid * CHUNK;
  int myd[EPT], mys[EPT];
#pragma unroll
  for (int i = 0; i < EPT; ++i) {
    int e = base + t + 256 * i;  // coalesced
    if (e < E) {
      myd[i] = dst[e];
      mys[i] = src[e];
      atomicAdd(&h[myd[i] >> BKSH], 1);
    } else myd[i] = -1;
  }
  __syncthreads();

  if (t < 64) {  // wave 0: exclusive scan of h[0..255], 4 per lane
    int i0 = 4 * t;
    int v0 = h[i0], v1 = h[i0 + 1], v2 = h[i0 + 2], v3 = h[i0 + 3];
    int s4 = v0 + v1 + v2 + v3, inc = s4;
#pragma unroll
    for (int off = 1; off < 64; off <<= 1) {
      int u = __shfl_up(inc, off, 64);
      if (t >= off) inc += u;
    }
    int ex = inc - s4;
    loff[i0] = ex; loff[i0 + 1] = ex + v0;
    loff[i0 + 2] = ex + v0 + v1; loff[i0 + 3] = ex + v0 + v1 + v2;
  }
  __syncthreads();

  if (t < NB) {
    if (h[t] > 0) gbase[t] = t * CAPE + atomicAdd(&cursor[t], h[t]);  // claim
  }
  __syncthreads();
  if (t < NBMAX) h[t] = 0;  // reuse as local cursor
  __syncthreads();

#pragma unroll
  for (int i = 0; i < EPT; ++i) {
    if (myd[i] >= 0) {
      int b = myd[i] >> BKSH;
      int p = atomicAdd(&h[b], 1);           // LDS int atomic: native, fast
      sbuf[loff[b] + p] = mys[i] | ((myd[i] & (BKN - 1)) << 17);  // src < 2^17
    }
  }
  __syncthreads();

  for (int b = w; b < NB; b += 4) {
    int c = h[b], lo = loff[b], go = gbase[b];
    for (int j = lane; j < c; j += 64)
      ebuf[go + j] = sbuf[lo + j];
  }
}

// Half-bucket csr: 392 blocks x 512 thr. Block bh sorts nodes
// [(bh&1)*256, +256) of bucket bh>>1. Reads the FULL bucket window, filters
// to its half, in-LDS node-sort, flushes to a PRIVATE col sub-window
// (bh*CAPH) — no cross-half dependency. rowse gets absolute col offsets.
// 2 blocks/CU co-resident + all 256 CUs covered (sb_csr was 1/CU on 196).
__global__ __launch_bounds__(512) void csr_half(
    const int* __restrict__ cursor, const int* __restrict__ ebuf,
    int* __restrict__ col, int2* __restrict__ rowse, int N) {
  __shared__ int sbuf[CAPH];   // 18432 B
  __shared__ int cnt[256];     //  1024 B
  __shared__ int wsum[4];
  __shared__ int nh_sh;        // total ~19.5 KB
  int bh = blockIdx.x, t = threadIdx.x;
  int b = bh >> 1, hf = bh & 1;
  int s = b * CAPE;
  int e = s + cursor[b];

  // stage full window, keep only this half's entries
  int my[WPT];
#pragma unroll
  for (int i = 0; i < WPT; ++i) {
    int j = s + t + i * BKN;
    int v = (j < e) ? ebuf[j] : -1;  // entries < 2^26, -1 safe sentinel
    int nl = (v >> 17) & (BKN - 1);
    my[i] = (v >= 0 && (nl >> 8) == hf) ? v : -1;
  }
  if (t < 256) cnt[t] = 0;
  __syncthreads();
#pragma unroll
  for (int i = 0; i < WPT; ++i)
    if (my[i] >= 0) atomicAdd(&cnt[(my[i] >> 17) & 255], 1);
  __syncthreads();

  // exclusive scan over 256 counts (threads 0..255, 4 waves)
  int lane = t & 63, w = t >> 6;
  int v = 0, inc = 0;
  if (t < 256) {
    v = cnt[t]; inc = v;
#pragma unroll
    for (int o = 1; o < 64; o <<= 1) {
      int u = __shfl_up(inc, o, 64);
      if (lane >= o) inc += u;
    }
    if (lane == 63) wsum[w] = inc;
  }
  __syncthreads();
  if (t < 4) {  // sources lanes 0..3, all active
    int s0 = wsum[t], incw = s0;
#pragma unroll
    for (int o = 1; o < 4; o <<= 1) {
      int u = __shfl_up(incw, o, 64);
      if (t >= o) incw += u;
    }
    wsum[t] = incw - s0;
    if (t == 3) nh_sh = incw;  // total kept in this half
  }
  __syncthreads();
  if (t < 256) {
    int ex = wsum[w] + inc - v;
    int node = (b << BKSH) + (hf << 8) + t;
    if (node < N) rowse[node] = make_int2(bh * CAPH + ex, v);
    cnt[t] = ex;  // seed scatter cursor with exclusive prefix
  }
  __syncthreads();

  // in-LDS node-sort: atomic result is the final position
#pragma unroll
  for (int i = 0; i < WPT; ++i) {
    if (my[i] >= 0) {
      int nl = (my[i] >> 17) & 255;
      int p = atomicAdd(&cnt[nl], 1);
      sbuf[p] = my[i] & 0x1FFFF;
    }
  }
  __syncthreads();

  // coalesced flush to private sub-window
  int nh = nh_sh;
  for (int j = t; j < nh; j += 512) col[bh * CAPH + j] = sbuf[j];
}

// Oct-per-node gather (unchanged from R13). 32 nodes/block (4 waves x 8
// octs). Lane owns 8 dims of its node -> no cross-lane reduce. Per 8 edges:
// one 32B col-line fetch per oct (prefetched one iteration ahead), then 8
// independent z-row loads. Loop bound = wave-max degree (uniform, shfl-safe);
// predicated-off lanes load z row 0 (L1-hot). All-64-lane epilogue writes.
__global__ __launch_bounds__(256) void gather_oct(
    const unsigned short* __restrict__ zb,
    const int2* __restrict__ rowse,
    const int* __restrict__ col,
    const unsigned short* __restrict__ yb,
    float* __restrict__ out, int N) {
  int t = threadIdx.x;
  int lane = t & 63, w = t >> 6;
  int o = lane >> 3, d = lane & 7;
  int node = blockIdx.x * 32 + w * 8 + o;

  int2 se = rowse[min(node, N - 1)];  // 8 lanes/oct same addr -> broadcast
  int s0 = se.x;
  int c = (node < N) ? se.y : 0;
  int cm1 = max(c - 1, 0);

  // wave-max degree (uniform trip count for the shfl loop)
  int cmax = c;
#pragma unroll
  for (int m = 8; m <= 32; m <<= 1) cmax = max(cmax, __shfl_xor(cmax, m, 64));

  long long ro = (long long)node * 64 + d * 8;
  long long ros = (long long)min(node, N - 1) * 64 + d * 8;
  short8 yv8 = *(const short8*)&yb[ros];  // prefetch, independent of edge loop

  float a[8] = {0.f, 0.f, 0.f, 0.f, 0.f, 0.f, 0.f, 0.f};
  float b2[8] = {0.f, 0.f, 0.f, 0.f, 0.f, 0.f, 0.f, 0.f};
  int colv = col[s0 + min(d, cm1)];  // first 32B line per oct
  for (int kb = 0; kb < cmax; kb += 8) {  // cmax wave-uniform
    int colv_nx = 0;
    if (kb + 8 < cmax) colv_nx = col[s0 + min(kb + 8 + d, cm1)];  // prefetch
#pragma unroll
    for (int j = 0; j < 8; ++j) {
      bool p = (kb + j) < c;  // oct-uniform predicate
      int cs = __shfl(colv, (lane & 56) | j, 64);  // all lanes active
      cs = p ? cs : 0;
      short8 v = *(const short8*)&zb[(long long)cs * 64 + d * 8];
      if (p) add8((j & 1) ? b2 : a, v);
    }
    colv = colv_nx;
  }
#pragma unroll
  for (int k = 0; k < 8; ++k) a[k] += b2[k];

  if (node < N) {
    float inv = 1.0f / fmaxf((float)c, 1.0f);
    float yv[8];
    cvt8(yv, yv8);
    float4 r0, r1;
    r0.x = fmaxf(yv[0] + a[0] * inv, 0.f);
    r0.y = fmaxf(yv[1] + a[1] * inv, 0.f);
    r0.z = fmaxf(yv[2] + a[2] * inv, 0.f);
    r0.w = fmaxf(yv[3] + a[3] * inv, 0.f);
    r1.x = fmaxf(yv[4] + a[4] * inv, 0.f);
    r1.y = fmaxf(yv[5] + a[5] * inv, 0.f);
    r1.z = fmaxf(yv[6] + a[6] * inv, 0.f);
    r1.w = fmaxf(yv[7] + a[7] * inv, 0.f);
    *(float4*)&out[ro] = r0;
    *(float4*)&out[ro + 4] = r1;
  }
}

extern "C" void kernel_launch(void* const* d_in, const int* in_sizes, int n_in,
                              void* d_out, int out_size, void* d_ws, size_t ws_size,
                              hipStream_t stream) {
  const float* x      = (const float*)d_in[0];
  const int*   eidx   = (const int*)d_in[1];
  const float* Wself  = (const float*)d_in[2];
  const float* bself  = (const float*)d_in[3];
  const float* Wneigh = (const float*)d_in[4];
  float* out = (float*)d_out;

  const int N = in_sizes[0] / 64;
  const int E = in_sizes[1] / 2;
  const int* src = eidx;      // edge_index row 0
  const int* dst = eidx + E;  // edge_index row 1
  const int NB = (N + BKN - 1) / BKN;       // 196 buckets of 512 nodes
  const int SCB = (E + CHUNK - 1) / CHUNK;  // 306 scatter blocks

  // ws layout: yb bf16[N*64] | zb bf16[N*64] | cursor[256] | rowse int2[N]
  //            | ebuf[NB*CAPE] | col[NB*2*CAPH]   (~39 MB)
  unsigned short* yb = (unsigned short*)d_ws;
  unsigned short* zb = yb + (size_t)N * 64;
  int* cursor = (int*)(zb + (size_t)N * 64);
  int2* rowse = (int2*)(cursor + NBMAX);
  int* ebuf   = (int*)(rowse + N);
  int* col    = ebuf + (size_t)NB * CAPE;

  hipMemsetAsync(cursor, 0, NBMAX * sizeof(int), stream);

  const int GB = (N + 63) / 64;  // 1563 GEMM blocks (64 nodes each)
  k1_main<<<SCB + GB, 256, 0, stream>>>(x, Wself, bself, Wneigh, yb, zb,
                                        src, dst, cursor, ebuf, E, N, NB, SCB);
  csr_half<<<NB * 2, 512, 0, stream>>>(cursor, ebuf, col, rowse, N);
  gather_oct<<<(N + 31) / 32, 256, 0, stream>>>(zb, rowse, col, yb, out, N);
}

// Round 16
// 146.449 us; speedup vs baseline: 1.1642x; 1.0762x over previous
//
#include <hip/hip_runtime.h>

// GCN layer: out = relu(x @ W_self^T + b_self + segment_mean(x[src], dst) @ W_neigh^T)
// N = 100000 nodes, D = 64, E = 1.25M edges.
//
// R3 structure: mean-then-matmul == matmul-then-mean (linearity).
// y = x@Ws^T + b and z = x@Wn^T computed FIRST (bf16 planes); gather averages
// z rows and finishes out = relu(y + mean).
// R4 lesson: per-edge scattered 4B global writes = 16x write amplification.
// R6 lesson: __shfl with divergent-exit loops is UB on gfx950 — all shfl loops
//   use wave-uniform trip counts with predication.
// R7-R15 lessons: nine theories falsified (LDS contention, block shape, claim
//   storm, dispatch count, fusion, TLP x2, store queue, csr halving). Fused
//   scatter||GEMM (R13) is the best front kernel; gather measures ~5.9 TB/s
//   effective (at BW ceiling); fill (~44 µs) is harness-fixed at 76% HBM.
//
// R16: theory #10 for k1's GEMM role — L1 WEIGHT THRASH. The two fp32 weight
// matrices are 32 KB = the entire per-CU L1; streaming x evicts them, so all
// 1563 GEMM blocks re-fetch weights from L2 inside the nt/ks loop (~200-300cy
// chains) and re-pack fp32->bf16 (16 pack8/thread) every block. Fix: stage
// both matrices ONCE per block into LDS as bf16 (16 KB in sbuf, unused by
// this role), XOR-swizzled (byte ^= (row&7)<<4) so the row-stride-128B
// ds_read_b128 is conflict-free (2-way = free, m136). Per-thread pack work
// drops 18->6 pack8. Stores: direct scalar (R12-proven equal).
//
// Pipeline (memset + 3 kernels):
//   memset      : cursor[256] = 0.
//   k1_main     : blocks [0,SCB): LDS-staged radix scatter into 196 buckets
//                 (contiguous-run claim, full-line ebuf writes). Blocks
//                 [SCB,+GB): dual MFMA GEMM -> bf16 y,z with LDS weights.
//   sb_csr      : one 512-thread block per bucket (R13-proven): window in
//                 regs, in-LDS node-sort, coalesced flush. LDS *int* atomics
//                 only (fp32 LDS atomicAdd = CAS-loop disaster).
//   gather_oct  : 3125 blocks x 256 thr, oct-per-node, 8-deep z ILP +
//                 col-line prefetch (unchanged; measured at BW ceiling).

#define BKSH 9                // log2(nodes per bucket)
#define BKN 512               // nodes per bucket
#define NBMAX 256             // >= NB = 196
#define CAPE 7168             // edge capacity per bucket (mean 6400, +9.6 sigma)
#define WPT (CAPE / BKN)      // window entries per thread in sb_csr = 14
#define CHUNK 4096            // edges per scatter block
#define EPT (CHUNK / 256)     // edges per thread in scatter = 16

typedef __attribute__((ext_vector_type(8))) short short8;
typedef __attribute__((ext_vector_type(4))) float floatx4;

// fp32 -> bf16 round-to-nearest-even, branch-free.
static __device__ inline unsigned short f2bf(float f) {
  union { float f; unsigned int u; } v;
  v.f = f;
  unsigned int r = v.u + 0x7FFFu + ((v.u >> 16) & 1u);
  return (unsigned short)(r >> 16);
}

static __device__ inline short8 pack8(float4 a, float4 b) {
  short8 s;
  s[0] = (short)f2bf(a.x); s[1] = (short)f2bf(a.y);
  s[2] = (short)f2bf(a.z); s[3] = (short)f2bf(a.w);
  s[4] = (short)f2bf(b.x); s[5] = (short)f2bf(b.y);
  s[6] = (short)f2bf(b.z); s[7] = (short)f2bf(b.w);
  return s;
}

// unpack 8 bf16 (4 dwords) and accumulate into 8 fp32.
static __device__ inline void add8(float* a, short8 sv) {
  union { short8 s; unsigned int u[4]; } c; c.s = sv;
#pragma unroll
  for (int i = 0; i < 4; ++i) {
    a[2 * i]     += __uint_as_float(c.u[i] << 16);
    a[2 * i + 1] += __uint_as_float(c.u[i] & 0xFFFF0000u);
  }
}

// unpack 8 bf16 into 8 fp32 (no accumulate).
static __device__ inline void cvt8(float* a, short8 sv) {
  union { short8 s; unsigned int u[4]; } c; c.s = sv;
#pragma unroll
  for (int i = 0; i < 4; ++i) {
    a[2 * i]     = __uint_as_float(c.u[i] << 16);
    a[2 * i + 1] = __uint_as_float(c.u[i] & 0xFFFF0000u);
  }
}

// Fused: edge radix-scatter (blocks < SCB) | dual-GEMM y,z from fp32 x.
__global__ __launch_bounds__(256) void k1_main(
    const float* __restrict__ x,
    const float* __restrict__ Wself, const float* __restrict__ bself,
    const float* __restrict__ Wneigh,
    unsigned short* __restrict__ yb, unsigned short* __restrict__ zb,
    const int* __restrict__ src, const int* __restrict__ dst,
    int* __restrict__ cursor, int* __restrict__ ebuf,
    int E, int N, int NB, int SCB) {
  __shared__ int h[NBMAX], loff[NBMAX], gbase[NBMAX];
  __shared__ int sbuf[CHUNK];
  int t = threadIdx.x;
  int bid = blockIdx.x;

  if (bid >= SCB) {
    // ---- GEMM role: y = x@Ws^T + b (bf16), z = x@Wn^T (bf16) ----
    // Stage BOTH weight matrices into LDS as bf16 once per block (16 KB in
    // sbuf), XOR-swizzled so the inner-loop ds_read_b128 at row stride 128B
    // is conflict-free. Kills the per-block L1-thrash L2 refetch (theory #10)
    // and cuts per-thread pack8 count 18 -> 6.
    int lane = t & 63;
    int w = t >> 6;
    int tb = (bid - SCB) * 64 + w * 16;
    int m = lane & 15, q = lane >> 4;
    char* wlds = (char*)sbuf;  // 16 KB: [mat][row 0..63][128B row, swizzled]

    for (int g = t; g < 1024; g += 256) {  // 512 groups per matrix
      int mat = g >> 9;
      int gg = g & 511;
      int row = gg >> 3, col8 = gg & 7;
      const float* p = (mat ? Wneigh : Wself) + row * 64 + col8 * 8;
      short8 v = pack8(*(const float4*)p, *(const float4*)(p + 4));
      int ba = (row * 128 + col8 * 16) ^ ((row & 7) << 4);  // swizzle
      *(short8*)(wlds + mat * 8192 + ba) = v;
    }

    long long rowA = (long long)min(tb + m, N - 1) * 64;
    short8 ax[2];
#pragma unroll
    for (int ks = 0; ks < 2; ++ks) {
      const float* xr = &x[rowA + ks * 32 + q * 8];
      ax[ks] = pack8(*(const float4*)xr, *(const float4*)(xr + 4));
    }
    __syncthreads();  // weights ready (block-uniform role -> barrier safe)

#pragma unroll
    for (int nt = 0; nt < 4; ++nt) {
      int ob = nt * 16;
      int row = ob + m;
      floatx4 accs = {0.f, 0.f, 0.f, 0.f};
      floatx4 accn = {0.f, 0.f, 0.f, 0.f};
#pragma unroll
      for (int ks = 0; ks < 2; ++ks) {
        int ba = (row * 128 + ks * 64 + q * 16) ^ ((row & 7) << 4);
        short8 bs = *(const short8*)(wlds + ba);
        accs = __builtin_amdgcn_mfma_f32_16x16x32_bf16(ax[ks], bs, accs, 0, 0, 0);
        short8 bn = *(const short8*)(wlds + 8192 + ba);
        accn = __builtin_amdgcn_mfma_f32_16x16x32_bf16(ax[ks], bn, accn, 0, 0, 0);
      }
      float bias = bself[row];
#pragma unroll
      for (int r = 0; r < 4; ++r) {
        int node = tb + q * 4 + r;
        if (node < N) {
          yb[(long long)node * 64 + row] = f2bf(accs[r] + bias);
          zb[(long long)node * 64 + row] = f2bf(accn[r]);
        }
      }
    }
    return;
  }

  // ---- scatter role ----
  int w = t >> 6, lane = t & 63;
  if (t < NBMAX) h[t] = 0;
  __syncthreads();

  int base = bid * CHUNK;
  int myd[EPT], mys[EPT];
#pragma unroll
  for (int i = 0; i < EPT; ++i) {
    int e = base + t + 256 * i;  // coalesced
    if (e < E) {
      myd[i] = dst[e];
      mys[i] = src[e];
      atomicAdd(&h[myd[i] >> BKSH], 1);
    } else myd[i] = -1;
  }
  __syncthreads();

  if (t < 64) {  // wave 0: exclusive scan of h[0..255], 4 per lane
    int i0 = 4 * t;
    int v0 = h[i0], v1 = h[i0 + 1], v2 = h[i0 + 2], v3 = h[i0 + 3];
    int s4 = v0 + v1 + v2 + v3, inc = s4;
#pragma unroll
    for (int off = 1; off < 64; off <<= 1) {
      int u = __shfl_up(inc, off, 64);
      if (t >= off) inc += u;
    }
    int ex = inc - s4;
    loff[i0] = ex; loff[i0 + 1] = ex + v0;
    loff[i0 + 2] = ex + v0 + v1; loff[i0 + 3] = ex + v0 + v1 + v2;
  }
  __syncthreads();

  if (t < NB) {
    if (h[t] > 0) gbase[t] = t * CAPE + atomicAdd(&cursor[t], h[t]);  // claim
  }
  __syncthreads();
  if (t < NBMAX) h[t] = 0;  // reuse as local cursor
  __syncthreads();

#pragma unroll
  for (int i = 0; i < EPT; ++i) {
    if (myd[i] >= 0) {
      int b = myd[i] >> BKSH;
      int p = atomicAdd(&h[b], 1);           // LDS int atomic: native, fast
      sbuf[loff[b] + p] = mys[i] | ((myd[i] & (BKN - 1)) << 17);  // src < 2^17
    }
  }
  __syncthreads();

  for (int b = w; b < NB; b += 4) {
    int c = h[b], lo = loff[b], go = gbase[b];
    for (int j = lane; j < c; j += 64)
      ebuf[go + j] = sbuf[lo + j];
  }
}

// One 512-thread block per 512-node bucket (196 blocks). Window read ONCE
// from global into registers; count -> block scan -> in-LDS node-sort ->
// coalesced flush. cnt[] doubles as scatter cursor (seeded with exclusive
// prefix), so the atomicAdd result IS the final sorted position.
__global__ __launch_bounds__(512) void sb_csr(const int* __restrict__ cursor,
                                              const int* __restrict__ ebuf,
                                              int* __restrict__ col,
                                              int2* __restrict__ rowse, int N) {
  __shared__ int sbuf[CAPE];   // 28672 B
  __shared__ int cnt[BKN];     //  2048 B
  __shared__ int wsum[8];      // total ~30.8 KB
  int b = blockIdx.x, t = threadIdx.x;
  int s = b * CAPE;
  int n = cursor[b];
  int e = s + n;

  // stage window into registers (static indices -> stays in VGPRs)
  int my[WPT];
#pragma unroll
  for (int i = 0; i < WPT; ++i) {
    int j = s + t + i * BKN;
    my[i] = (j < e) ? ebuf[j] : -1;  // entries < 2^26, -1 is a safe sentinel
  }

  cnt[t] = 0;
  __syncthreads();
#pragma unroll
  for (int i = 0; i < WPT; ++i)
    if (my[i] >= 0) atomicAdd(&cnt[(my[i] >> 17) & (BKN - 1)], 1);
  __syncthreads();

  // block exclusive scan over 512 (1 per thread, 8 waves)
  int v = cnt[t];
  int lane = t & 63, w = t >> 6;
  int inc = v;
#pragma unroll
  for (int o = 1; o < 64; o <<= 1) {
    int u = __shfl_up(inc, o, 64);
    if (lane >= o) inc += u;
  }
  if (lane == 63) wsum[w] = inc;
  __syncthreads();
  if (t < 8) {
    int s0 = wsum[t], incw = s0;
#pragma unroll
    for (int o = 1; o < 8; o <<= 1) {
      int u = __shfl_up(incw, o, 64);
      if (t >= o) incw += u;
    }
    wsum[t] = incw - s0;
  }
  __syncthreads();
  int ex = wsum[w] + inc - v;
  int node = (b << BKSH) + t;
  if (node < N) rowse[node] = make_int2(s + ex, v);
  __syncthreads();
  cnt[t] = ex;  // seed scatter cursor with exclusive prefix
  __syncthreads();

  // in-LDS node-sort: atomic result is the final position in the window
#pragma unroll
  for (int i = 0; i < WPT; ++i) {
    if (my[i] >= 0) {
      int nl = (my[i] >> 17) & (BKN - 1);
      int p = atomicAdd(&cnt[nl], 1);
      sbuf[p] = my[i] & 0x1FFFF;
    }
  }
  __syncthreads();

  // coalesced flush
  for (int j = t; j < n; j += BKN) col[s + j] = sbuf[j];
}

// Oct-per-node gather (unchanged from R13; measures ~5.9 TB/s effective —
// at the BW ceiling). 32 nodes/block (4 waves x 8 octs). Lane owns 8 dims of
// its node -> no cross-lane reduce. Per 8 edges: one 32B col-line fetch per
// oct (prefetched one iteration ahead), then 8 independent z-row loads.
// Loop bound = wave-max degree (uniform, shfl-safe); predicated-off lanes
// load z row 0 (L1-hot). All-64-lane epilogue writes.
__global__ __launch_bounds__(256) void gather_oct(
    const unsigned short* __restrict__ zb,
    const int2* __restrict__ rowse,
    const int* __restrict__ col,
    const unsigned short* __restrict__ yb,
    float* __restrict__ out, int N) {
  int t = threadIdx.x;
  int lane = t & 63, w = t >> 6;
  int o = lane >> 3, d = lane & 7;
  int node = blockIdx.x * 32 + w * 8 + o;

  int2 se = rowse[min(node, N - 1)];  // 8 lanes/oct same addr -> broadcast
  int s0 = se.x;
  int c = (node < N) ? se.y : 0;
  int cm1 = max(c - 1, 0);

  // wave-max degree (uniform trip count for the shfl loop)
  int cmax = c;
#pragma unroll
  for (int m = 8; m <= 32; m <<= 1) cmax = max(cmax, __shfl_xor(cmax, m, 64));

  long long ro = (long long)node * 64 + d * 8;
  long long ros = (long long)min(node, N - 1) * 64 + d * 8;
  short8 yv8 = *(const short8*)&yb[ros];  // prefetch, independent of edge loop

  float a[8] = {0.f, 0.f, 0.f, 0.f, 0.f, 0.f, 0.f, 0.f};
  float b2[8] = {0.f, 0.f, 0.f, 0.f, 0.f, 0.f, 0.f, 0.f};
  int colv = col[s0 + min(d, cm1)];  // first 32B line per oct
  for (int kb = 0; kb < cmax; kb += 8) {  // cmax wave-uniform
    int colv_nx = 0;
    if (kb + 8 < cmax) colv_nx = col[s0 + min(kb + 8 + d, cm1)];  // prefetch
#pragma unroll
    for (int j = 0; j < 8; ++j) {
      bool p = (kb + j) < c;  // oct-uniform predicate
      int cs = __shfl(colv, (lane & 56) | j, 64);  // all lanes active
      cs = p ? cs : 0;
      short8 v = *(const short8*)&zb[(long long)cs * 64 + d * 8];
      if (p) add8((j & 1) ? b2 : a, v);
    }
    colv = colv_nx;
  }
#pragma unroll
  for (int k = 0; k < 8; ++k) a[k] += b2[k];

  if (node < N) {
    float inv = 1.0f / fmaxf((float)c, 1.0f);
    float yv[8];
    cvt8(yv, yv8);
    float4 r0, r1;
    r0.x = fmaxf(yv[0] + a[0] * inv, 0.f);
    r0.y = fmaxf(yv[1] + a[1] * inv, 0.f);
    r0.z = fmaxf(yv[2] + a[2] * inv, 0.f);
    r0.w = fmaxf(yv[3] + a[3] * inv, 0.f);
    r1.x = fmaxf(yv[4] + a[4] * inv, 0.f);
    r1.y = fmaxf(yv[5] + a[5] * inv, 0.f);
    r1.z = fmaxf(yv[6] + a[6] * inv, 0.f);
    r1.w = fmaxf(yv[7] + a[7] * inv, 0.f);
    *(float4*)&out[ro] = r0;
    *(float4*)&out[ro + 4] = r1;
  }
}

extern "C" void kernel_launch(void* const* d_in, const int* in_sizes, int n_in,
                              void* d_out, int out_size, void* d_ws, size_t ws_size,
                              hipStream_t stream) {
  const float* x      = (const float*)d_in[0];
  const int*   eidx   = (const int*)d_in[1];
  const float* Wself  = (const float*)d_in[2];
  const float* bself  = (const float*)d_in[3];
  const float* Wneigh = (const float*)d_in[4];
  float* out = (float*)d_out;

  const int N = in_sizes[0] / 64;
  const int E = in_sizes[1] / 2;
  const int* src = eidx;      // edge_index row 0
  const int* dst = eidx + E;  // edge_index row 1
  const int NB = (N + BKN - 1) / BKN;       // 196 buckets of 512 nodes
  const int SCB = (E + CHUNK - 1) / CHUNK;  // 306 scatter blocks

  // ws layout: yb bf16[N*64] | zb bf16[N*64] | cursor[256] | rowse int2[N]
  //            | ebuf[NB*CAPE] | col[NB*CAPE]   (~38 MB)
  unsigned short* yb = (unsigned short*)d_ws;
  unsigned short* zb = yb + (size_t)N * 64;
  int* cursor = (int*)(zb + (size_t)N * 64);
  int2* rowse = (int2*)(cursor + NBMAX);
  int* ebuf   = (int*)(rowse + N);
  int* col    = ebuf + (size_t)NB * CAPE;

  hipMemsetAsync(cursor, 0, NBMAX * sizeof(int), stream);

  const int GB = (N + 63) / 64;  // 1563 GEMM blocks (64 nodes each)
  k1_main<<<SCB + GB, 256, 0, stream>>>(x, Wself, bself, Wneigh, yb, zb,
                                        src, dst, cursor, ebuf, E, N, NB, SCB);
  sb_csr<<<NB, BKN, 0, stream>>>(cursor, ebuf, col, rowse, N);
  gather_oct<<<(N + 31) / 32, 256, 0, stream>>>(zb, rowse, col, yb, out, N);
}

// Round 17
// 142.951 us; speedup vs baseline: 1.1927x; 1.0245x over previous
//
#include <hip/hip_runtime.h>

// GCN layer: out = relu(x @ W_self^T + b_self + segment_mean(x[src], dst) @ W_neigh^T)
// N = 100000 nodes, D = 64, E = 1.25M edges.
//
// R3 structure: mean-then-matmul == matmul-then-mean (linearity).
// y = x@Ws^T + b and z = x@Wn^T computed FIRST (bf16 planes); gather averages
// z rows and finishes out = relu(y + mean).
// R4 lesson: per-edge scattered 4B global writes = 16x write amplification.
// R6 lesson: __shfl whose SOURCE lane may have exited a divergent loop is UB.
//   Refined in R17: the constraint is on the source lane's liveness, not on
//   wave-uniformity of the trip count. Intra-oct shfl with an oct-uniform
//   bound is safe (an oct exits only as a whole).
// R7-R15: nine falsified theories (LDS contention, block shape, claim storm,
//   dispatch count, fusion, TLP x2, store queue, csr halving).
// R16 WIN (theory #10 confirmed): GEMM-role L1 weight thrash — staging both
//   weight matrices in LDS as bf16 (XOR-swizzled) cut total 156.5 -> 146.4.
//
// R17: gather issue-waste fix. The inner loop bound drops from WAVE-max
// degree (~21 avg: 40% predicated-off slots still issuing shfl+loads) to the
// per-oct node degree c (oct-uniform). All shfl sources are intra-oct
// ((lane&56)|j), so per-oct exit keeps every source lane active. Everything
// else frozen from R16.
//
// Pipeline (memset + 3 kernels):
//   memset      : cursor[256] = 0.
//   k1_main     : blocks [0,SCB): LDS-staged radix scatter into 196 buckets
//                 (contiguous-run claim, full-line ebuf writes). Blocks
//                 [SCB,+GB): dual MFMA GEMM -> bf16 y,z with LDS-resident
//                 bf16 weights (16 KB, swizzled; R16 win).
//   sb_csr      : one 512-thread block per bucket: window in regs, in-LDS
//                 node-sort, coalesced flush. LDS *int* atomics only
//                 (fp32 LDS atomicAdd = CAS-loop disaster).
//   gather_oct  : 3125 blocks x 256 thr, oct-per-node, 8-deep z ILP,
//                 col-line prefetch, per-oct trip count.

#define BKSH 9                // log2(nodes per bucket)
#define BKN 512               // nodes per bucket
#define NBMAX 256             // >= NB = 196
#define CAPE 7168             // edge capacity per bucket (mean 6400, +9.6 sigma)
#define WPT (CAPE / BKN)      // window entries per thread in sb_csr = 14
#define CHUNK 4096            // edges per scatter block
#define EPT (CHUNK / 256)     // edges per thread in scatter = 16

typedef __attribute__((ext_vector_type(8))) short short8;
typedef __attribute__((ext_vector_type(4))) float floatx4;

// fp32 -> bf16 round-to-nearest-even, branch-free.
static __device__ inline unsigned short f2bf(float f) {
  union { float f; unsigned int u; } v;
  v.f = f;
  unsigned int r = v.u + 0x7FFFu + ((v.u >> 16) & 1u);
  return (unsigned short)(r >> 16);
}

static __device__ inline short8 pack8(float4 a, float4 b) {
  short8 s;
  s[0] = (short)f2bf(a.x); s[1] = (short)f2bf(a.y);
  s[2] = (short)f2bf(a.z); s[3] = (short)f2bf(a.w);
  s[4] = (short)f2bf(b.x); s[5] = (short)f2bf(b.y);
  s[6] = (short)f2bf(b.z); s[7] = (short)f2bf(b.w);
  return s;
}

// unpack 8 bf16 (4 dwords) and accumulate into 8 fp32.
static __device__ inline void add8(float* a, short8 sv) {
  union { short8 s; unsigned int u[4]; } c; c.s = sv;
#pragma unroll
  for (int i = 0; i < 4; ++i) {
    a[2 * i]     += __uint_as_float(c.u[i] << 16);
    a[2 * i + 1] += __uint_as_float(c.u[i] & 0xFFFF0000u);
  }
}

// unpack 8 bf16 into 8 fp32 (no accumulate).
static __device__ inline void cvt8(float* a, short8 sv) {
  union { short8 s; unsigned int u[4]; } c; c.s = sv;
#pragma unroll
  for (int i = 0; i < 4; ++i) {
    a[2 * i]     = __uint_as_float(c.u[i] << 16);
    a[2 * i + 1] = __uint_as_float(c.u[i] & 0xFFFF0000u);
  }
}

// Fused: edge radix-scatter (blocks < SCB) | dual-GEMM y,z from fp32 x.
__global__ __launch_bounds__(256) void k1_main(
    const float* __restrict__ x,
    const float* __restrict__ Wself, const float* __restrict__ bself,
    const float* __restrict__ Wneigh,
    unsigned short* __restrict__ yb, unsigned short* __restrict__ zb,
    const int* __restrict__ src, const int* __restrict__ dst,
    int* __restrict__ cursor, int* __restrict__ ebuf,
    int E, int N, int NB, int SCB) {
  __shared__ int h[NBMAX], loff[NBMAX], gbase[NBMAX];
  __shared__ int sbuf[CHUNK];
  int t = threadIdx.x;
  int bid = blockIdx.x;

  if (bid >= SCB) {
    // ---- GEMM role: y = x@Ws^T + b (bf16), z = x@Wn^T (bf16) ----
    // Both weight matrices staged into LDS as bf16 once per block (16 KB in
    // sbuf), XOR-swizzled -> conflict-free ds_read_b128 (R16 win: kills the
    // per-block L1-thrash L2 refetch; pack8 per thread 18 -> 6).
    int lane = t & 63;
    int w = t >> 6;
    int tb = (bid - SCB) * 64 + w * 16;
    int m = lane & 15, q = lane >> 4;
    char* wlds = (char*)sbuf;  // 16 KB: [mat][row 0..63][128B row, swizzled]

    for (int g = t; g < 1024; g += 256) {  // 512 groups per matrix
      int mat = g >> 9;
      int gg = g & 511;
      int row = gg >> 3, col8 = gg & 7;
      const float* p = (mat ? Wneigh : Wself) + row * 64 + col8 * 8;
      short8 v = pack8(*(const float4*)p, *(const float4*)(p + 4));
      int ba = (row * 128 + col8 * 16) ^ ((row & 7) << 4);  // swizzle
      *(short8*)(wlds + mat * 8192 + ba) = v;
    }

    long long rowA = (long long)min(tb + m, N - 1) * 64;
    short8 ax[2];
#pragma unroll
    for (int ks = 0; ks < 2; ++ks) {
      const float* xr = &x[rowA + ks * 32 + q * 8];
      ax[ks] = pack8(*(const float4*)xr, *(const float4*)(xr + 4));
    }
    __syncthreads();  // weights ready (block-uniform role -> barrier safe)

#pragma unroll
    for (int nt = 0; nt < 4; ++nt) {
      int ob = nt * 16;
      int row = ob + m;
      floatx4 accs = {0.f, 0.f, 0.f, 0.f};
      floatx4 accn = {0.f, 0.f, 0.f, 0.f};
#pragma unroll
      for (int ks = 0; ks < 2; ++ks) {
        int ba = (row * 128 + ks * 64 + q * 16) ^ ((row & 7) << 4);
        short8 bs = *(const short8*)(wlds + ba);
        accs = __builtin_amdgcn_mfma_f32_16x16x32_bf16(ax[ks], bs, accs, 0, 0, 0);
        short8 bn = *(const short8*)(wlds + 8192 + ba);
        accn = __builtin_amdgcn_mfma_f32_16x16x32_bf16(ax[ks], bn, accn, 0, 0, 0);
      }
      float bias = bself[row];
#pragma unroll
      for (int r = 0; r < 4; ++r) {
        int node = tb + q * 4 + r;
        if (node < N) {
          yb[(long long)node * 64 + row] = f2bf(accs[r] + bias);
          zb[(long long)node * 64 + row] = f2bf(accn[r]);
        }
      }
    }
    return;
  }

  // ---- scatter role ----
  int w = t >> 6, lane = t & 63;
  if (t < NBMAX) h[t] = 0;
  __syncthreads();

  int base = bid * CHUNK;
  int myd[EPT], mys[EPT];
#pragma unroll
  for (int i = 0; i < EPT; ++i) {
    int e = base + t + 256 * i;  // coalesced
    if (e < E) {
      myd[i] = dst[e];
      mys[i] = src[e];
      atomicAdd(&h[myd[i] >> BKSH], 1);
    } else myd[i] = -1;
  }
  __syncthreads();

  if (t < 64) {  // wave 0: exclusive scan of h[0..255], 4 per lane
    int i0 = 4 * t;
    int v0 = h[i0], v1 = h[i0 + 1], v2 = h[i0 + 2], v3 = h[i0 + 3];
    int s4 = v0 + v1 + v2 + v3, inc = s4;
#pragma unroll
    for (int off = 1; off < 64; off <<= 1) {
      int u = __shfl_up(inc, off, 64);
      if (t >= off) inc += u;
    }
    int ex = inc - s4;
    loff[i0] = ex; loff[i0 + 1] = ex + v0;
    loff[i0 + 2] = ex + v0 + v1; loff[i0 + 3] = ex + v0 + v1 + v2;
  }
  __syncthreads();

  if (t < NB) {
    if (h[t] > 0) gbase[t] = t * CAPE + atomicAdd(&cursor[t], h[t]);  // claim
  }
  __syncthreads();
  if (t < NBMAX) h[t] = 0;  // reuse as local cursor
  __syncthreads();

#pragma unroll
  for (int i = 0; i < EPT; ++i) {
    if (myd[i] >= 0) {
      int b = myd[i] >> BKSH;
      int p = atomicAdd(&h[b], 1);           // LDS int atomic: native, fast
      sbuf[loff[b] + p] = mys[i] | ((myd[i] & (BKN - 1)) << 17);  // src < 2^17
    }
  }
  __syncthreads();

  for (int b = w; b < NB; b += 4) {
    int c = h[b], lo = loff[b], go = gbase[b];
    for (int j = lane; j < c; j += 64)
      ebuf[go + j] = sbuf[lo + j];
  }
}

// One 512-thread block per 512-node bucket (196 blocks). Window read ONCE
// from global into registers; count -> block scan -> in-LDS node-sort ->
// coalesced flush. cnt[] doubles as scatter cursor (seeded with exclusive
// prefix), so the atomicAdd result IS the final sorted position.
__global__ __launch_bounds__(512) void sb_csr(const int* __restrict__ cursor,
                                              const int* __restrict__ ebuf,
                                              int* __restrict__ col,
                                              int2* __restrict__ rowse, int N) {
  __shared__ int sbuf[CAPE];   // 28672 B
  __shared__ int cnt[BKN];     //  2048 B
  __shared__ int wsum[8];      // total ~30.8 KB
  int b = blockIdx.x, t = threadIdx.x;
  int s = b * CAPE;
  int n = cursor[b];
  int e = s + n;

  // stage window into registers (static indices -> stays in VGPRs)
  int my[WPT];
#pragma unroll
  for (int i = 0; i < WPT; ++i) {
    int j = s + t + i * BKN;
    my[i] = (j < e) ? ebuf[j] : -1;  // entries < 2^26, -1 is a safe sentinel
  }

  cnt[t] = 0;
  __syncthreads();
#pragma unroll
  for (int i = 0; i < WPT; ++i)
    if (my[i] >= 0) atomicAdd(&cnt[(my[i] >> 17) & (BKN - 1)], 1);
  __syncthreads();

  // block exclusive scan over 512 (1 per thread, 8 waves)
  int v = cnt[t];
  int lane = t & 63, w = t >> 6;
  int inc = v;
#pragma unroll
  for (int o = 1; o < 64; o <<= 1) {
    int u = __shfl_up(inc, o, 64);
    if (lane >= o) inc += u;
  }
  if (lane == 63) wsum[w] = inc;
  __syncthreads();
  if (t < 8) {
    int s0 = wsum[t], incw = s0;
#pragma unroll
    for (int o = 1; o < 8; o <<= 1) {
      int u = __shfl_up(incw, o, 64);
      if (t >= o) incw += u;
    }
    wsum[t] = incw - s0;
  }
  __syncthreads();
  int ex = wsum[w] + inc - v;
  int node = (b << BKSH) + t;
  if (node < N) rowse[node] = make_int2(s + ex, v);
  __syncthreads();
  cnt[t] = ex;  // seed scatter cursor with exclusive prefix
  __syncthreads();

  // in-LDS node-sort: atomic result is the final position in the window
#pragma unroll
  for (int i = 0; i < WPT; ++i) {
    if (my[i] >= 0) {
      int nl = (my[i] >> 17) & (BKN - 1);
      int p = atomicAdd(&cnt[nl], 1);
      sbuf[p] = my[i] & 0x1FFFF;
    }
  }
  __syncthreads();

  // coalesced flush
  for (int j = t; j < n; j += BKN) col[s + j] = sbuf[j];
}

// Oct-per-node gather. 32 nodes/block (4 waves x 8 octs). Lane owns 8 dims
// of its node -> no cross-lane reduce. Per 8 edges: one 32B col-line fetch
// per oct (prefetched one iteration ahead), then 8 independent z-row loads.
// R17: trip count is the PER-OCT degree c (oct-uniform) instead of wave-max:
// every __shfl source is intra-oct ((lane&56)|j) and an oct exits only as a
// whole, so all source lanes stay active (R6 constraint refined). ~40% fewer
// issued inner iterations. Predicated-off lanes in the tail load z row 0
// (L1-hot). All-64-lane epilogue writes.
__global__ __launch_bounds__(256) void gather_oct(
    const unsigned short* __restrict__ zb,
    const int2* __restrict__ rowse,
    const int* __restrict__ col,
    const unsigned short* __restrict__ yb,
    float* __restrict__ out, int N) {
  int t = threadIdx.x;
  int lane = t & 63, w = t >> 6;
  int o = lane >> 3, d = lane & 7;
  int node = blockIdx.x * 32 + w * 8 + o;

  int2 se = rowse[min(node, N - 1)];  // 8 lanes/oct same addr -> broadcast
  int s0 = se.x;
  int c = (node < N) ? se.y : 0;      // oct-uniform
  int cm1 = max(c - 1, 0);

  long long ro = (long long)node * 64 + d * 8;
  long long ros = (long long)min(node, N - 1) * 64 + d * 8;
  short8 yv8 = *(const short8*)&yb[ros];  // prefetch, independent of edge loop

  float a[8] = {0.f, 0.f, 0.f, 0.f, 0.f, 0.f, 0.f, 0.f};
  float b2[8] = {0.f, 0.f, 0.f, 0.f, 0.f, 0.f, 0.f, 0.f};
  int colv = col[s0 + min(d, cm1)];  // first 32B line per oct
  for (int kb = 0; kb < c; kb += 8) {  // per-oct bound; shfl strictly intra-oct
    int colv_nx = 0;
    if (kb + 8 < c) colv_nx = col[s0 + min(kb + 8 + d, cm1)];  // prefetch
#pragma unroll
    for (int j = 0; j < 8; ++j) {
      bool p = (kb + j) < c;  // oct-uniform predicate
      int cs = __shfl(colv, (lane & 56) | j, 64);  // source within own oct
      cs = p ? cs : 0;
      short8 v = *(const short8*)&zb[(long long)cs * 64 + d * 8];
      if (p) add8((j & 1) ? b2 : a, v);
    }
    colv = colv_nx;
  }
#pragma unroll
  for (int k = 0; k < 8; ++k) a[k] += b2[k];

  if (node < N) {
    float inv = 1.0f / fmaxf((float)c, 1.0f);
    float yv[8];
    cvt8(yv, yv8);
    float4 r0, r1;
    r0.x = fmaxf(yv[0] + a[0] * inv, 0.f);
    r0.y = fmaxf(yv[1] + a[1] * inv, 0.f);
    r0.z = fmaxf(yv[2] + a[2] * inv, 0.f);
    r0.w = fmaxf(yv[3] + a[3] * inv, 0.f);
    r1.x = fmaxf(yv[4] + a[4] * inv, 0.f);
    r1.y = fmaxf(yv[5] + a[5] * inv, 0.f);
    r1.z = fmaxf(yv[6] + a[6] * inv, 0.f);
    r1.w = fmaxf(yv[7] + a[7] * inv, 0.f);
    *(float4*)&out[ro] = r0;
    *(float4*)&out[ro + 4] = r1;
  }
}

extern "C" void kernel_launch(void* const* d_in, const int* in_sizes, int n_in,
                              void* d_out, int out_size, void* d_ws, size_t ws_size,
                              hipStream_t stream) {
  const float* x      = (const float*)d_in[0];
  const int*   eidx   = (const int*)d_in[1];
  const float* Wself  = (const float*)d_in[2];
  const float* bself  = (const float*)d_in[3];
  const float* Wneigh = (const float*)d_in[4];
  float* out = (float*)d_out;

  const int N = in_sizes[0] / 64;
  const int E = in_sizes[1] / 2;
  const int* src = eidx;      // edge_index row 0
  const int* dst = eidx + E;  // edge_index row 1
  const int NB = (N + BKN - 1) / BKN;       // 196 buckets of 512 nodes
  const int SCB = (E + CHUNK - 1) / CHUNK;  // 306 scatter blocks

  // ws layout: yb bf16[N*64] | zb bf16[N*64] | cursor[256] | rowse int2[N]
  //            | ebuf[NB*CAPE] | col[NB*CAPE]   (~38 MB)
  unsigned short* yb = (unsigned short*)d_ws;
  unsigned short* zb = yb + (size_t)N * 64;
  int* cursor = (int*)(zb + (size_t)N * 64);
  int2* rowse = (int2*)(cursor + NBMAX);
  int* ebuf   = (int*)(rowse + N);
  int* col    = ebuf + (size_t)NB * CAPE;

  hipMemsetAsync(cursor, 0, NBMAX * sizeof(int), stream);

  const int GB = (N + 63) / 64;  // 1563 GEMM blocks (64 nodes each)
  k1_main<<<SCB + GB, 256, 0, stream>>>(x, Wself, bself, Wneigh, yb, zb,
                                        src, dst, cursor, ebuf, E, N, NB, SCB);
  sb_csr<<<NB, BKN, 0, stream>>>(cursor, ebuf, col, rowse, N);
  gather_oct<<<(N + 31) / 32, 256, 0, stream>>>(zb, rowse, col, yb, out, N);
}